// Round 2
// baseline (148.451 us; speedup 1.0000x reference)
//
#include <hip/hip_runtime.h>
#include <stdint.h>

#define NB 16
#define CC 32
#define HH 224
#define WWID 224
#define HWS (HH*WWID)          // 50176
#define NHWT (NB*HWS)          // 802816
#define TOT (NB*CC*HWS)        // 25690112

// ---------- pack weights: (32,32,3,3) fp32 -> 288 x {signbits, nzbits} ----------
__global__ void pack_w(const float* __restrict__ w, uint2* __restrict__ wp) {
    int k = threadIdx.x;               // co*9 + tap
    if (k >= CC * 9) return;
    int co = k / 9, tap = k % 9;
    unsigned bits = 0, nz = 0;
    for (int ci = 0; ci < CC; ++ci) {
        float v = w[(co * CC + ci) * 9 + tap];
        bits |= (v > 0.f ? 1u : 0u) << ci;
        nz   |= (v != 0.f ? 1u : 0u) << ci;
    }
    wp[k] = make_uint2(bits, nz);
}

// ---------- pack x: 4 pixels/thread, float4 loads ----------
__global__ void __launch_bounds__(256) pack_x4(const float* __restrict__ x,
                                               uint2* __restrict__ xp) {
    int t = blockIdx.x * 256 + threadIdx.x;
    int p4 = t * 4;
    int n = p4 / HWS, hw = p4 - n * HWS;        // hw multiple of 4
    const float* base = x + (size_t)n * CC * HWS + hw;
    unsigned b0=0,b1=0,b2=0,b3=0, z0=0,z1=0,z2=0,z3=0;
    #pragma unroll
    for (int c = 0; c < CC; ++c) {
        float4 v = *(const float4*)(base + (size_t)c * HWS);
        b0 |= (v.x > 0.f ? (1u<<c) : 0u);  z0 |= (v.x != 0.f ? (1u<<c) : 0u);
        b1 |= (v.y > 0.f ? (1u<<c) : 0u);  z1 |= (v.y != 0.f ? (1u<<c) : 0u);
        b2 |= (v.z > 0.f ? (1u<<c) : 0u);  z2 |= (v.z != 0.f ? (1u<<c) : 0u);
        b3 |= (v.w > 0.f ? (1u<<c) : 0u);  z3 |= (v.w != 0.f ? (1u<<c) : 0u);
    }
    uint4* o = (uint4*)(xp + p4);
    o[0] = make_uint4(b0, z0, b1, z1);
    o[1] = make_uint4(b2, z2, b3, z3);
}

// ---------- shared conv core: 4 horizontal pixels, one cout ----------
__device__ __forceinline__ void conv_y4(const unsigned xb[3][6], const unsigned xn[3][6],
                                        const uint2* __restrict__ wq, int y[4]) {
    #pragma unroll
    for (int px = 0; px < 4; ++px) {
        int am = 0, ad = 0;
        #pragma unroll
        for (int kh = 0; kh < 3; ++kh) {
            #pragma unroll
            for (int kw = 0; kw < 3; ++kw) {
                uint2 q = wq[kh * 3 + kw];          // uniform -> s_load
                unsigned m = xn[kh][px + kw] & q.y;
                am += __popc(m);
                ad += __popc((xb[kh][px + kw] ^ q.x) & m);
            }
        }
        y[px] = am - 2 * ad;
    }
}

// ---------- load the 3x6 packed neighborhood for a 1x4 pixel strip ----------
__device__ __forceinline__ void load_nbhd(const uint2* __restrict__ xpn, int h, int w0,
                                          unsigned xb[3][6], unsigned xn[3][6]) {
    #pragma unroll
    for (int rr = 0; rr < 3; ++rr) {
        int hh = h - 1 + rr;
        bool rv = (unsigned)hh < (unsigned)HH;
        #pragma unroll
        for (int cc = 0; cc < 6; ++cc) {
            int ww = w0 - 1 + cc;
            bool v = rv && ((unsigned)ww < (unsigned)WWID);
            uint2 t = v ? xpn[hh * WWID + ww] : make_uint2(0u, 0u);
            xb[rr][cc] = t.x; xn[rr][cc] = t.y;
        }
    }
}

// ---------- pass A: conv recompute + exact per-channel stats ----------
__global__ void __launch_bounds__(256) convstats(const uint2* __restrict__ xp,
                                                 const uint2* __restrict__ wp,
                                                 int* __restrict__ s_sum,
                                                 unsigned long long* __restrict__ s_sq) {
    __shared__ int ls[4][CC];
    __shared__ int lq[4][CC];
    int tid = blockIdx.x * 256 + threadIdx.x;
    int n = tid / 12544, rem = tid - n * 12544;
    int h = rem / 56, w0 = (rem - h * 56) * 4;
    const uint2* xpn = xp + n * HWS;

    unsigned xb[3][6], xn_[3][6];
    load_nbhd(xpn, h, w0, xb, xn_);

    int lane = threadIdx.x & 63, wid = threadIdx.x >> 6;
    for (int cg = 0; cg < 8; ++cg) {
        int sv[4], qv[4];
        #pragma unroll
        for (int u = 0; u < 4; ++u) {
            int co = cg * 4 + u;
            int y[4];
            conv_y4(xb, xn_, wp + co * 9, y);
            int s = 0, q = 0;
            #pragma unroll
            for (int px = 0; px < 4; ++px) { s += y[px]; q += y[px] * y[px]; }
            sv[u] = s; qv[u] = q;
        }
        #pragma unroll
        for (int off = 32; off; off >>= 1) {
            #pragma unroll
            for (int u = 0; u < 4; ++u) {
                sv[u] += __shfl_down(sv[u], off);
                qv[u] += __shfl_down(qv[u], off);
            }
        }
        if (lane == 0) {
            #pragma unroll
            for (int u = 0; u < 4; ++u) { ls[wid][cg*4+u] = sv[u]; lq[wid][cg*4+u] = qv[u]; }
        }
    }
    __syncthreads();
    if (threadIdx.x < CC) {
        int c = threadIdx.x;
        int S = ls[0][c] + ls[1][c] + ls[2][c] + ls[3][c];
        int Q = lq[0][c] + lq[1][c] + lq[2][c] + lq[3][c];
        atomicAdd(&s_sum[c], S);
        atomicAdd(&s_sq[c], (unsigned long long)Q);
    }
}

// ---------- finalize BN: scale/shift per channel ----------
__global__ void bfinal(const int* __restrict__ s_sum,
                       const unsigned long long* __restrict__ s_sq,
                       const float* __restrict__ gamma, const float* __restrict__ beta,
                       float* __restrict__ scale, float* __restrict__ shift) {
    int c = threadIdx.x;
    if (c >= CC) return;
    double mean = (double)s_sum[c] / (double)NHWT;
    double var  = (double)(long long)s_sq[c] / (double)NHWT - mean * mean;
    float inv = (float)(1.0 / sqrt(var + 1e-5));
    float g = gamma[c] * inv;
    scale[c] = g;
    shift[c] = beta[c] - (float)mean * g;
}

// ---------- pass B: conv recompute + normalize + store ----------
__global__ void __launch_bounds__(256) convnorm(const uint2* __restrict__ xp,
                                                const uint2* __restrict__ wp,
                                                const float* __restrict__ scale,
                                                const float* __restrict__ shift,
                                                float* __restrict__ out) {
    int tid = blockIdx.x * 256 + threadIdx.x;
    int n = tid / 12544, rem = tid - n * 12544;
    int h = rem / 56, w0 = (rem - h * 56) * 4;
    const uint2* xpn = xp + n * HWS;

    unsigned xb[3][6], xn_[3][6];
    load_nbhd(xpn, h, w0, xb, xn_);

    float* on = out + (size_t)n * CC * HWS + h * WWID + w0;
    for (int cg = 0; cg < 8; ++cg) {
        #pragma unroll
        for (int u = 0; u < 4; ++u) {
            int co = cg * 4 + u;
            int y[4];
            conv_y4(xb, xn_, wp + co * 9, y);
            float sc = scale[co], sh = shift[co];
            float4 o = make_float4(y[0] * sc + sh, y[1] * sc + sh,
                                   y[2] * sc + sh, y[3] * sc + sh);
            *(float4*)(on + (size_t)co * HWS) = o;
        }
    }
}

extern "C" void kernel_launch(void* const* d_in, const int* in_sizes, int n_in,
                              void* d_out, int out_size, void* d_ws, size_t ws_size,
                              hipStream_t stream) {
    const float* x     = (const float*)d_in[0];
    const float* w     = (const float*)d_in[1];
    const float* gamma = (const float*)d_in[2];
    const float* beta  = (const float*)d_in[3];
    float* out = (float*)d_out;

    char* ws = (char*)d_ws;
    uint2* wpk               = (uint2*)(ws);                      // 2304 B
    int* s_sum               = (int*)(ws + 4096);                 // 128 B
    unsigned long long* s_sq = (unsigned long long*)(ws + 4352);  // 256 B
    float* scale             = (float*)(ws + 4608);               // 128 B
    float* shift             = (float*)(ws + 4736);               // 128 B
    uint2* xpk               = (uint2*)(ws + 8192);               // 6,422,528 B

    // zero the atomic accumulators every launch
    hipMemsetAsync(ws + 4096, 0, 768, stream);

    pack_w  <<<1, 320, 0, stream>>>(w, wpk);
    pack_x4 <<<NHWT / 4 / 256, 256, 0, stream>>>(x, xpk);
    convstats<<<NHWT / 4 / 256, 256, 0, stream>>>(xpk, wpk, s_sum, s_sq);
    bfinal  <<<1, 64, 0, stream>>>(s_sum, s_sq, gamma, beta, scale, shift);
    convnorm<<<NHWT / 4 / 256, 256, 0, stream>>>(xpk, wpk, scale, shift, out);
}

// Round 3
// 134.420 us; speedup vs baseline: 1.1044x; 1.1044x over previous
//
#include <hip/hip_runtime.h>
#include <stdint.h>

#define NB 16
#define CC 32
#define HH 224
#define WWID 224
#define HWS (HH*WWID)          // 50176
#define NHWT (NB*HWS)          // 802816
#define STRIPS (NHWT/4)        // 200704 (1x4 pixel strips)
#define SPI (HWS/4)            // 12544 strips per image
#define SPR (WWID/4)           // 56 strips per row

// workspace layout (bytes)
#define WS_WSIGN 0             // 288 * 4
#define WS_WNZ   2048          // 288 * 4
#define WS_FLAGW 4096          // int: all weights nonzero
#define WS_FLAGZ 4100          // int: some x is zero (memset 0)
#define WS_SSUM  4352          // 32 * int
#define WS_SSQ   4608          // 32 * ull
#define WS_SCALE 4864          // 32 * float
#define WS_SHIFT 4992          // 32 * float
#define WS_XS    8192          // NHWT * 4  (sign bits)
#define WS_XNZ   (8192 + (size_t)NHWT * 4)   // NHWT * 4  (nonzero bits)

// ---------- pack weights + all-nonzero flag ----------
__global__ void pack_w(const float* __restrict__ w, unsigned* __restrict__ wsg,
                       unsigned* __restrict__ wnz, int* __restrict__ flagw) {
    __shared__ int allnz;
    if (threadIdx.x == 0) allnz = 1;
    __syncthreads();
    int k = threadIdx.x;               // co*9 + tap
    if (k < CC * 9) {
        int co = k / 9, tap = k % 9;
        unsigned bits = 0, nz = 0;
        for (int ci = 0; ci < CC; ++ci) {
            float v = w[(co * CC + ci) * 9 + tap];
            bits |= (v > 0.f ? 1u : 0u) << ci;
            nz   |= (v != 0.f ? 1u : 0u) << ci;
        }
        wsg[k] = bits; wnz[k] = nz;
        if (nz != 0xffffffffu) atomicAnd(&allnz, 0);
    }
    __syncthreads();
    if (threadIdx.x == 0) *flagw = allnz;
}

// ---------- pack x: 4 px/thread, float4 loads; sets zero-found flag ----------
__global__ void __launch_bounds__(256) pack_x4(const float* __restrict__ x,
                                               unsigned* __restrict__ xs,
                                               unsigned* __restrict__ xnz,
                                               int* __restrict__ flagz) {
    int t = blockIdx.x * 256 + threadIdx.x;     // strip id
    int n = t / SPI, hw = (t - n * SPI) * 4;
    const float* base = x + (size_t)n * CC * HWS + hw;
    unsigned b0=0,b1=0,b2=0,b3=0, z0=0,z1=0,z2=0,z3=0;
    #pragma unroll
    for (int c = 0; c < CC; ++c) {
        float4 v = *(const float4*)(base + (size_t)c * HWS);
        b0 |= (v.x > 0.f ? (1u<<c) : 0u);  z0 |= (v.x != 0.f ? (1u<<c) : 0u);
        b1 |= (v.y > 0.f ? (1u<<c) : 0u);  z1 |= (v.y != 0.f ? (1u<<c) : 0u);
        b2 |= (v.z > 0.f ? (1u<<c) : 0u);  z2 |= (v.z != 0.f ? (1u<<c) : 0u);
        b3 |= (v.w > 0.f ? (1u<<c) : 0u);  z3 |= (v.w != 0.f ? (1u<<c) : 0u);
    }
    *(uint4*)(xs  + (size_t)t * 4) = make_uint4(b0, b1, b2, b3);
    *(uint4*)(xnz + (size_t)t * 4) = make_uint4(z0, z1, z2, z3);
    bool hasz = (z0 & z1 & z2 & z3) != 0xffffffffu;
    if (__any(hasz) && (threadIdx.x & 63) == 0) atomicOr(flagz, 1);
}

// ---------- neighborhood loads ----------
__device__ __forceinline__ void load_sig(const unsigned* __restrict__ xsn, int h, int w0,
                                         unsigned xb[3][6], unsigned vm[3][6]) {
    #pragma unroll
    for (int rr = 0; rr < 3; ++rr) {
        int hh = h - 1 + rr;
        bool rv = (unsigned)hh < (unsigned)HH;
        #pragma unroll
        for (int cc = 0; cc < 6; ++cc) {
            int ww = w0 - 1 + cc;
            bool v = rv && ((unsigned)ww < (unsigned)WWID);
            vm[rr][cc] = v ? 0xffffffffu : 0u;
            xb[rr][cc] = v ? xsn[hh * WWID + ww] : 0u;
        }
    }
}

__device__ __forceinline__ void load_nz(const unsigned* __restrict__ xzn, int h, int w0,
                                        unsigned xn[3][6]) {
    #pragma unroll
    for (int rr = 0; rr < 3; ++rr) {
        int hh = h - 1 + rr;
        bool rv = (unsigned)hh < (unsigned)HH;
        #pragma unroll
        for (int cc = 0; cc < 6; ++cc) {
            int ww = w0 - 1 + cc;
            bool v = rv && ((unsigned)ww < (unsigned)WWID);
            xn[rr][cc] = v ? xzn[hh * WWID + ww] : 0u;
        }
    }
}

// y for 4 px, one co — fast interior: y = 288 - 2*sum popc(xor)
__device__ __forceinline__ void y4_fast_int(const unsigned xb[3][6],
                                            const unsigned* __restrict__ q, int y[4]) {
    #pragma unroll
    for (int px = 0; px < 4; ++px) {
        int t = 0;
        #pragma unroll
        for (int kh = 0; kh < 3; ++kh)
            #pragma unroll
            for (int kw = 0; kw < 3; ++kw)
                t += __popc(xb[kh][px + kw] ^ q[kh * 3 + kw]);
        y[px] = 288 - 2 * t;
    }
}

// fast boundary: y = 32*nvalid - 2*sum popc((xor)&vm)
__device__ __forceinline__ void y4_fast_bnd(const unsigned xb[3][6], const unsigned vm[3][6],
                                            const int nv[4],
                                            const unsigned* __restrict__ q, int y[4]) {
    #pragma unroll
    for (int px = 0; px < 4; ++px) {
        int t = 0;
        #pragma unroll
        for (int kh = 0; kh < 3; ++kh)
            #pragma unroll
            for (int kw = 0; kw < 3; ++kw)
                t += __popc((xb[kh][px + kw] ^ q[kh * 3 + kw]) & vm[kh][px + kw]);
        y[px] = 32 * nv[px] - 2 * t;
    }
}

// generic exact path (handles zeros anywhere)
__device__ __forceinline__ void y4_slow(const unsigned xb[3][6], const unsigned xn[3][6],
                                        const unsigned* __restrict__ qs,
                                        const unsigned* __restrict__ qz, int y[4]) {
    #pragma unroll
    for (int px = 0; px < 4; ++px) {
        int am = 0, ad = 0;
        #pragma unroll
        for (int kh = 0; kh < 3; ++kh)
            #pragma unroll
            for (int kw = 0; kw < 3; ++kw) {
                int k = kh * 3 + kw;
                unsigned m = xn[kh][px + kw] & qz[k];
                am += __popc(m);
                ad += __popc((xb[kh][px + kw] ^ qs[k]) & m);
            }
        y[px] = am - 2 * ad;
    }
}

// ---------- pass A: conv + exact per-channel stats (8 couts per block) ----------
__global__ void __launch_bounds__(256) convstats(const unsigned* __restrict__ xs,
                                                 const unsigned* __restrict__ xnz,
                                                 const unsigned* __restrict__ wsg,
                                                 const unsigned* __restrict__ wnz,
                                                 const int* __restrict__ flagw,
                                                 const int* __restrict__ flagz,
                                                 int* __restrict__ s_sum,
                                                 unsigned long long* __restrict__ s_sq) {
    int gco = blockIdx.x & 3, cobase = gco * 8;
    int ts = (blockIdx.x >> 2) * 256 + threadIdx.x;
    int n = ts / SPI, rem = ts - n * SPI;
    int h = rem / SPR, w0 = (rem - h * SPR) * 4;
    const unsigned* xsn = xs + (size_t)n * HWS;

    unsigned xb[3][6], vm[3][6];
    load_sig(xsn, h, w0, xb, vm);

    int sacc[8], qacc[8];
    bool fast = (*flagw != 0) && (*flagz == 0);
    if (fast) {
        bool interior = (h >= 1) && (h <= HH - 2) && (w0 >= 1) && (w0 <= WWID - 5);
        if (interior) {
            #pragma unroll
            for (int u = 0; u < 8; ++u) {
                int y[4];
                y4_fast_int(xb, wsg + (cobase + u) * 9, y);
                int s = 0, qq = 0;
                #pragma unroll
                for (int px = 0; px < 4; ++px) { s += y[px]; qq += y[px] * y[px]; }
                sacc[u] = s; qacc[u] = qq;
            }
        } else {
            int nv[4];
            #pragma unroll
            for (int px = 0; px < 4; ++px) {
                int t = 0;
                #pragma unroll
                for (int kh = 0; kh < 3; ++kh)
                    #pragma unroll
                    for (int kw = 0; kw < 3; ++kw) t += (int)(vm[kh][px + kw] & 1u);
                nv[px] = t;
            }
            #pragma unroll
            for (int u = 0; u < 8; ++u) {
                int y[4];
                y4_fast_bnd(xb, vm, nv, wsg + (cobase + u) * 9, y);
                int s = 0, qq = 0;
                #pragma unroll
                for (int px = 0; px < 4; ++px) { s += y[px]; qq += y[px] * y[px]; }
                sacc[u] = s; qacc[u] = qq;
            }
        }
    } else {
        unsigned xn[3][6];
        load_nz(xnz + (size_t)n * HWS, h, w0, xn);
        #pragma unroll
        for (int u = 0; u < 8; ++u) {
            int y[4];
            y4_slow(xb, xn, wsg + (cobase + u) * 9, wnz + (cobase + u) * 9, y);
            int s = 0, qq = 0;
            #pragma unroll
            for (int px = 0; px < 4; ++px) { s += y[px]; qq += y[px] * y[px]; }
            sacc[u] = s; qacc[u] = qq;
        }
    }

    #pragma unroll
    for (int off = 32; off; off >>= 1) {
        #pragma unroll
        for (int u = 0; u < 8; ++u) {
            sacc[u] += __shfl_down(sacc[u], off);
            qacc[u] += __shfl_down(qacc[u], off);   // wave sum <= 64*4*288^2 fits int32
        }
    }
    __shared__ int ls[4][8], lq[4][8];
    int wid = threadIdx.x >> 6, lane = threadIdx.x & 63;
    if (lane == 0) {
        #pragma unroll
        for (int u = 0; u < 8; ++u) { ls[wid][u] = sacc[u]; lq[wid][u] = qacc[u]; }
    }
    __syncthreads();
    if (threadIdx.x < 8) {
        int u = threadIdx.x;
        int S = ls[0][u] + ls[1][u] + ls[2][u] + ls[3][u];
        long long Q = (long long)lq[0][u] + lq[1][u] + lq[2][u] + lq[3][u];
        atomicAdd(&s_sum[cobase + u], S);
        atomicAdd(&s_sq[cobase + u], (unsigned long long)Q);
    }
}

// ---------- finalize BN ----------
__global__ void bfinal(const int* __restrict__ s_sum,
                       const unsigned long long* __restrict__ s_sq,
                       const float* __restrict__ gamma, const float* __restrict__ beta,
                       float* __restrict__ scale, float* __restrict__ shift) {
    int c = threadIdx.x;
    if (c >= CC) return;
    double mean = (double)s_sum[c] / (double)NHWT;
    double var  = (double)(long long)s_sq[c] / (double)NHWT - mean * mean;
    float inv = (float)(1.0 / sqrt(var + 1e-5));
    float g = gamma[c] * inv;
    scale[c] = g;
    shift[c] = beta[c] - (float)mean * g;
}

// ---------- pass B: conv + normalize + store (8 couts per block) ----------
__global__ void __launch_bounds__(256) convnorm(const unsigned* __restrict__ xs,
                                                const unsigned* __restrict__ xnz,
                                                const unsigned* __restrict__ wsg,
                                                const unsigned* __restrict__ wnz,
                                                const int* __restrict__ flagw,
                                                const int* __restrict__ flagz,
                                                const float* __restrict__ scale,
                                                const float* __restrict__ shift,
                                                float* __restrict__ out) {
    int gco = blockIdx.x & 3, cobase = gco * 8;
    int ts = (blockIdx.x >> 2) * 256 + threadIdx.x;
    int n = ts / SPI, rem = ts - n * SPI;
    int h = rem / SPR, w0 = (rem - h * SPR) * 4;
    const unsigned* xsn = xs + (size_t)n * HWS;

    unsigned xb[3][6], vm[3][6];
    load_sig(xsn, h, w0, xb, vm);

    float* on = out + (size_t)n * CC * HWS + h * WWID + w0;
    bool fast = (*flagw != 0) && (*flagz == 0);
    if (fast) {
        bool interior = (h >= 1) && (h <= HH - 2) && (w0 >= 1) && (w0 <= WWID - 5);
        if (interior) {
            #pragma unroll
            for (int u = 0; u < 8; ++u) {
                int co = cobase + u;
                int y[4];
                y4_fast_int(xb, wsg + co * 9, y);
                float sc = scale[co], sh = shift[co];
                *(float4*)(on + (size_t)co * HWS) =
                    make_float4(y[0]*sc+sh, y[1]*sc+sh, y[2]*sc+sh, y[3]*sc+sh);
            }
        } else {
            int nv[4];
            #pragma unroll
            for (int px = 0; px < 4; ++px) {
                int t = 0;
                #pragma unroll
                for (int kh = 0; kh < 3; ++kh)
                    #pragma unroll
                    for (int kw = 0; kw < 3; ++kw) t += (int)(vm[kh][px + kw] & 1u);
                nv[px] = t;
            }
            #pragma unroll
            for (int u = 0; u < 8; ++u) {
                int co = cobase + u;
                int y[4];
                y4_fast_bnd(xb, vm, nv, wsg + co * 9, y);
                float sc = scale[co], sh = shift[co];
                *(float4*)(on + (size_t)co * HWS) =
                    make_float4(y[0]*sc+sh, y[1]*sc+sh, y[2]*sc+sh, y[3]*sc+sh);
            }
        }
    } else {
        unsigned xn[3][6];
        load_nz(xnz + (size_t)n * HWS, h, w0, xn);
        #pragma unroll
        for (int u = 0; u < 8; ++u) {
            int co = cobase + u;
            int y[4];
            y4_slow(xb, xn, wsg + co * 9, wnz + co * 9, y);
            float sc = scale[co], sh = shift[co];
            *(float4*)(on + (size_t)co * HWS) =
                make_float4(y[0]*sc+sh, y[1]*sc+sh, y[2]*sc+sh, y[3]*sc+sh);
        }
    }
}

extern "C" void kernel_launch(void* const* d_in, const int* in_sizes, int n_in,
                              void* d_out, int out_size, void* d_ws, size_t ws_size,
                              hipStream_t stream) {
    const float* x     = (const float*)d_in[0];
    const float* w     = (const float*)d_in[1];
    const float* gamma = (const float*)d_in[2];
    const float* beta  = (const float*)d_in[3];
    float* out = (float*)d_out;

    char* ws = (char*)d_ws;
    unsigned* wsg            = (unsigned*)(ws + WS_WSIGN);
    unsigned* wnz            = (unsigned*)(ws + WS_WNZ);
    int* flagw               = (int*)(ws + WS_FLAGW);
    int* flagz               = (int*)(ws + WS_FLAGZ);
    int* s_sum               = (int*)(ws + WS_SSUM);
    unsigned long long* s_sq = (unsigned long long*)(ws + WS_SSQ);
    float* scale             = (float*)(ws + WS_SCALE);
    float* shift             = (float*)(ws + WS_SHIFT);
    unsigned* xsb            = (unsigned*)(ws + WS_XS);
    unsigned* xzb            = (unsigned*)(ws + WS_XNZ);

    // zero flagz + stat accumulators (covers 4100..4864)
    hipMemsetAsync(ws + WS_FLAGZ, 0, 764, stream);

    pack_w  <<<1, 320, 0, stream>>>(w, wsg, wnz, flagw);
    pack_x4 <<<STRIPS / 256, 256, 0, stream>>>(x, xsb, xzb, flagz);
    convstats<<<STRIPS / 256 * 4, 256, 0, stream>>>(xsb, xzb, wsg, wnz, flagw, flagz,
                                                    s_sum, s_sq);
    bfinal  <<<1, 64, 0, stream>>>(s_sum, s_sq, gamma, beta, scale, shift);
    convnorm<<<STRIPS / 256 * 4, 256, 0, stream>>>(xsb, xzb, wsg, wnz, flagw, flagz,
                                                   scale, shift, out);
}

// Round 4
// 91.722 us; speedup vs baseline: 1.6185x; 1.4655x over previous
//
#include <hip/hip_runtime.h>
#include <stdint.h>

#define NB 16
#define CC 32
#define HH 224
#define WWID 224
#define HWS (HH*WWID)          // 50176
#define NHWT (NB*HWS)          // 802816
#define STRIPS (NHWT/4)        // 200704 (1x4 pixel strips)
#define SPI (HWS/4)            // 12544 strips per image
#define SPR (WWID/4)           // 56 strips per row

// padded packed-bit image: 1-col left halo (col = 1+w), rows = 1+h, zero border
#define PITCH 232              // dwords per padded row (16B-aligned rows)
#define PROWS 226
#define IMGW (PITCH*PROWS)     // 52432 dwords per padded image

typedef float    f4 __attribute__((ext_vector_type(4)));
typedef unsigned u4 __attribute__((ext_vector_type(4)));
typedef unsigned u2 __attribute__((ext_vector_type(2)));

// workspace layout (bytes)
#define WS_WSIGN 0                       // 288 * 4
#define WS_WNZ   2048                    // 288 * 4
#define WS_BASE  4096                    // 288 * 4 (9 classes x 32 co)
#define WS_FLAGW 5248
#define WS_FLAGZ 5252
#define WS_SSUM  5376                    // 32 * int
#define WS_SSQ   5632                    // 32 * ull (8-aligned)
#define WS_SCALE 5888                    // 32 * float
#define WS_SHIFT 6016                    // 32 * float
#define WS_XS    8192                    // 16 * IMGW * 4 = 3,355,648
#define WS_XNZ   (8192 + (size_t)NB*IMGW*4)

// ---------- pack weights + all-nonzero flag + boundary base table ----------
__global__ void pack_w(const float* __restrict__ w, unsigned* __restrict__ wsg,
                       unsigned* __restrict__ wnz, int* __restrict__ flagw,
                       int* __restrict__ baset) {
    __shared__ unsigned s_sg[288];
    __shared__ int allnz;
    if (threadIdx.x == 0) allnz = 1;
    __syncthreads();
    int k = threadIdx.x;
    if (k < 288) {
        int co = k / 9, tap = k % 9;
        unsigned bits = 0, nz = 0;
        for (int ci = 0; ci < CC; ++ci) {
            float v = w[(co * CC + ci) * 9 + tap];
            bits |= (v > 0.f ? 1u : 0u) << ci;
            nz   |= (v != 0.f ? 1u : 0u) << ci;
        }
        wsg[k] = bits; wnz[k] = nz; s_sg[k] = bits;
        if (nz != 0xffffffffu) atomicAnd(&allnz, 0);
    }
    __syncthreads();
    if (threadIdx.x == 0) *flagw = allnz;
    if (k < 288) {
        int cls = k >> 5, co = k & 31;
        int hc = cls / 3, wc = cls % 3;
        int nv = 0, corr = 0;
        #pragma unroll
        for (int kh = 0; kh < 3; ++kh)
            #pragma unroll
            for (int kw = 0; kw < 3; ++kw) {
                bool inv = (hc == 0 && kh == 0) || (hc == 2 && kh == 2) ||
                           (wc == 0 && kw == 0) || (wc == 2 && kw == 2);
                if (inv) corr += __popc(s_sg[co * 9 + kh * 3 + kw]);
                else     nv++;
            }
        baset[k] = 32 * nv + 2 * corr;   // y = base - 2*sum9 popc(xor), halo xb = 0
    }
}

// ---------- pack x into padded sign/nz bit images ----------
__global__ void __launch_bounds__(256) pack_x4(const float* __restrict__ x,
                                               unsigned* __restrict__ xs,
                                               unsigned* __restrict__ xnz,
                                               int* __restrict__ flagz) {
    int t = blockIdx.x * 256 + threadIdx.x;     // strip id
    int n = t / SPI, rem = t - n * SPI;
    int h = rem / SPR, w0 = (rem - h * SPR) * 4;
    const float* base = x + (size_t)n * CC * HWS + h * WWID + w0;
    unsigned b0=0,b1=0,b2=0,b3=0, z0=0,z1=0,z2=0,z3=0;
    #pragma unroll
    for (int c = 0; c < CC; ++c) {
        f4 v = __builtin_nontemporal_load((const f4*)(base + (size_t)c * HWS));
        b0 |= (v.x > 0.f ? (1u<<c) : 0u);  z0 |= (v.x != 0.f ? (1u<<c) : 0u);
        b1 |= (v.y > 0.f ? (1u<<c) : 0u);  z1 |= (v.y != 0.f ? (1u<<c) : 0u);
        b2 |= (v.z > 0.f ? (1u<<c) : 0u);  z2 |= (v.z != 0.f ? (1u<<c) : 0u);
        b3 |= (v.w > 0.f ? (1u<<c) : 0u);  z3 |= (v.w != 0.f ? (1u<<c) : 0u);
    }
    size_t d = (size_t)n * IMGW + (h + 1) * PITCH + 1 + w0;
    xs[d+0]=b0; xs[d+1]=b1; xs[d+2]=b2; xs[d+3]=b3;
    xnz[d+0]=z0; xnz[d+1]=z1; xnz[d+2]=z2; xnz[d+3]=z3;
    bool hasz = (z0 & z1 & z2 & z3) != 0xffffffffu;
    if (__any(hasz) && (threadIdx.x & 63) == 0) atomicOr(flagz, 1);
}

// ---------- window load: 6 dwords of one padded row (aligned x4 + x2) ----------
__device__ __forceinline__ void loadwin(const unsigned* __restrict__ p, unsigned a[6]) {
    u4 lo = *(const u4*)p;          // cols w0..w0+3 (16B aligned)
    u2 hi = *(const u2*)(p + 4);    // cols w0+4..w0+5 (8B aligned)
    a[0]=lo.x; a[1]=lo.y; a[2]=lo.z; a[3]=lo.w; a[4]=hi.x; a[5]=hi.y;
}

// ---------- 4-px xor-popcount sums for one cout ----------
__device__ __forceinline__ void ad4(const unsigned a0[6], const unsigned a1[6],
                                    const unsigned a2[6],
                                    const unsigned* __restrict__ q, int ad[4]) {
    unsigned q0=q[0],q1=q[1],q2=q[2],q3=q[3],q4=q[4],q5=q[5],q6=q[6],q7=q[7],q8=q[8];
    #pragma unroll
    for (int px = 0; px < 4; ++px) {
        ad[px] = __popc(a0[px]^q0) + __popc(a0[px+1]^q1) + __popc(a0[px+2]^q2)
               + __popc(a1[px]^q3) + __popc(a1[px+1]^q4) + __popc(a1[px+2]^q5)
               + __popc(a2[px]^q6) + __popc(a2[px+1]^q7) + __popc(a2[px+2]^q8);
    }
}

// ---------- generic (zeros-allowed) 4-px conv for one cout ----------
__device__ __forceinline__ void y4_slowc(const unsigned a0[6], const unsigned a1[6],
                                         const unsigned a2[6], const unsigned z0[6],
                                         const unsigned z1[6], const unsigned z2[6],
                                         const unsigned* __restrict__ qs,
                                         const unsigned* __restrict__ qz, int y[4]) {
    #pragma unroll
    for (int px = 0; px < 4; ++px) {
        int am = 0, ad = 0;
        #pragma unroll
        for (int kw = 0; kw < 3; ++kw) {
            unsigned m0 = z0[px+kw] & qz[kw];
            unsigned m1 = z1[px+kw] & qz[3+kw];
            unsigned m2 = z2[px+kw] & qz[6+kw];
            am += __popc(m0) + __popc(m1) + __popc(m2);
            ad += __popc((a0[px+kw]^qs[kw])   & m0)
                + __popc((a1[px+kw]^qs[3+kw]) & m1)
                + __popc((a2[px+kw]^qs[6+kw]) & m2);
        }
        y[px] = am - 2 * ad;
    }
}

// ---------- pass A (fast): conv + exact per-channel stats, 8 couts/block ----------
__global__ void __launch_bounds__(256, 4) convstats_fast(
        const unsigned* __restrict__ xs, const unsigned* __restrict__ wsg,
        const int* __restrict__ baset, const int* __restrict__ flagw,
        const int* __restrict__ flagz, int* __restrict__ s_sum,
        unsigned long long* __restrict__ s_sq) {
    if (!(*flagw) || *flagz) return;
    __shared__ int sb[288];
    __shared__ int ls[4][8], lq[4][8];
    for (int i = threadIdx.x; i < 288; i += 256) sb[i] = baset[i];
    __syncthreads();

    int cobase = (blockIdx.x & 3) * 8;
    int sid = (blockIdx.x >> 2) * 256 + threadIdx.x;
    int n = sid / SPI, rem = sid - n * SPI;
    int h = rem / SPR, w0 = (rem - h * SPR) * 4;
    const unsigned* ip = xs + (size_t)n * IMGW + h * PITCH + w0;

    unsigned a0[6], a1[6], a2[6];
    loadwin(ip, a0); loadwin(ip + PITCH, a1); loadwin(ip + 2 * PITCH, a2);

    int hc = (h == 0) ? 0 : ((h == HH-1) ? 6 : 3);
    int c0 = (hc + ((w0 == 0) ? 0 : 1)) * 32;
    int c1 = (hc + 1) * 32;
    int c3 = (hc + ((w0 == WWID-4) ? 2 : 1)) * 32;

    int sacc[8], qacc[8];
    #pragma unroll
    for (int u = 0; u < 8; ++u) {
        int co = cobase + u;
        int ad[4];
        ad4(a0, a1, a2, wsg + co * 9, ad);
        int y0 = sb[c0 + co] - 2 * ad[0];
        int y1 = sb[c1 + co] - 2 * ad[1];
        int y2 = sb[c1 + co] - 2 * ad[2];
        int y3 = sb[c3 + co] - 2 * ad[3];
        sacc[u] = y0 + y1 + y2 + y3;
        qacc[u] = y0*y0 + y1*y1 + y2*y2 + y3*y3;
    }

    #pragma unroll
    for (int off = 32; off; off >>= 1) {
        #pragma unroll
        for (int u = 0; u < 8; ++u) {
            sacc[u] += __shfl_down(sacc[u], off);
            qacc[u] += __shfl_down(qacc[u], off);   // wave sum <= 64*4*288^2, fits int32
        }
    }
    int wid = threadIdx.x >> 6, lane = threadIdx.x & 63;
    if (lane == 0) {
        #pragma unroll
        for (int u = 0; u < 8; ++u) { ls[wid][u] = sacc[u]; lq[wid][u] = qacc[u]; }
    }
    __syncthreads();
    if (threadIdx.x < 8) {
        int u = threadIdx.x;
        int S = ls[0][u] + ls[1][u] + ls[2][u] + ls[3][u];
        long long Q = (long long)lq[0][u] + lq[1][u] + lq[2][u] + lq[3][u];
        atomicAdd(&s_sum[cobase + u], S);
        atomicAdd(&s_sq[cobase + u], (unsigned long long)Q);
    }
}

// ---------- pass A (slow/generic) ----------
__global__ void __launch_bounds__(256, 2) convstats_slow(
        const unsigned* __restrict__ xs, const unsigned* __restrict__ xnz,
        const unsigned* __restrict__ wsg, const unsigned* __restrict__ wnz,
        const int* __restrict__ flagw, const int* __restrict__ flagz,
        int* __restrict__ s_sum, unsigned long long* __restrict__ s_sq) {
    if ((*flagw) && !(*flagz)) return;
    __shared__ int ls[4][8], lq[4][8];
    int cobase = (blockIdx.x & 3) * 8;
    int sid = (blockIdx.x >> 2) * 256 + threadIdx.x;
    int n = sid / SPI, rem = sid - n * SPI;
    int h = rem / SPR, w0 = (rem - h * SPR) * 4;
    size_t off = (size_t)n * IMGW + h * PITCH + w0;

    unsigned a0[6], a1[6], a2[6], z0[6], z1[6], z2[6];
    loadwin(xs + off, a0); loadwin(xs + off + PITCH, a1); loadwin(xs + off + 2*PITCH, a2);
    loadwin(xnz + off, z0); loadwin(xnz + off + PITCH, z1); loadwin(xnz + off + 2*PITCH, z2);

    int sacc[8], qacc[8];
    #pragma unroll
    for (int u = 0; u < 8; ++u) {
        int co = cobase + u;
        int y[4];
        y4_slowc(a0, a1, a2, z0, z1, z2, wsg + co * 9, wnz + co * 9, y);
        sacc[u] = y[0]+y[1]+y[2]+y[3];
        qacc[u] = y[0]*y[0]+y[1]*y[1]+y[2]*y[2]+y[3]*y[3];
    }
    #pragma unroll
    for (int offv = 32; offv; offv >>= 1) {
        #pragma unroll
        for (int u = 0; u < 8; ++u) {
            sacc[u] += __shfl_down(sacc[u], offv);
            qacc[u] += __shfl_down(qacc[u], offv);
        }
    }
    int wid = threadIdx.x >> 6, lane = threadIdx.x & 63;
    if (lane == 0) {
        #pragma unroll
        for (int u = 0; u < 8; ++u) { ls[wid][u] = sacc[u]; lq[wid][u] = qacc[u]; }
    }
    __syncthreads();
    if (threadIdx.x < 8) {
        int u = threadIdx.x;
        int S = ls[0][u] + ls[1][u] + ls[2][u] + ls[3][u];
        long long Q = (long long)lq[0][u] + lq[1][u] + lq[2][u] + lq[3][u];
        atomicAdd(&s_sum[cobase + u], S);
        atomicAdd(&s_sq[cobase + u], (unsigned long long)Q);
    }
}

// ---------- finalize BN ----------
__global__ void bfinal(const int* __restrict__ s_sum,
                       const unsigned long long* __restrict__ s_sq,
                       const float* __restrict__ gamma, const float* __restrict__ beta,
                       float* __restrict__ scale, float* __restrict__ shift) {
    int c = threadIdx.x;
    if (c >= CC) return;
    double mean = (double)s_sum[c] / (double)NHWT;
    double var  = (double)(long long)s_sq[c] / (double)NHWT - mean * mean;
    float inv = (float)(1.0 / sqrt(var + 1e-5));
    float g = gamma[c] * inv;
    scale[c] = g;
    shift[c] = beta[c] - (float)mean * g;
}

// ---------- pass B (fast): conv + normalize + nt store, 8 couts/block ----------
__global__ void __launch_bounds__(256, 4) convnorm_fast(
        const unsigned* __restrict__ xs, const unsigned* __restrict__ wsg,
        const int* __restrict__ baset, const int* __restrict__ flagw,
        const int* __restrict__ flagz, const float* __restrict__ scale,
        const float* __restrict__ shift, float* __restrict__ out) {
    if (!(*flagw) || *flagz) return;
    __shared__ int sb[288];
    for (int i = threadIdx.x; i < 288; i += 256) sb[i] = baset[i];
    __syncthreads();

    int cobase = (blockIdx.x & 3) * 8;
    int sid = (blockIdx.x >> 2) * 256 + threadIdx.x;
    int n = sid / SPI, rem = sid - n * SPI;
    int h = rem / SPR, w0 = (rem - h * SPR) * 4;
    const unsigned* ip = xs + (size_t)n * IMGW + h * PITCH + w0;

    unsigned a0[6], a1[6], a2[6];
    loadwin(ip, a0); loadwin(ip + PITCH, a1); loadwin(ip + 2 * PITCH, a2);

    int hc = (h == 0) ? 0 : ((h == HH-1) ? 6 : 3);
    int c0 = (hc + ((w0 == 0) ? 0 : 1)) * 32;
    int c1 = (hc + 1) * 32;
    int c3 = (hc + ((w0 == WWID-4) ? 2 : 1)) * 32;

    float* on = out + (size_t)(n * CC + cobase) * HWS + h * WWID + w0;
    #pragma unroll
    for (int u = 0; u < 8; ++u) {
        int co = cobase + u;
        int ad[4];
        ad4(a0, a1, a2, wsg + co * 9, ad);
        int y0 = sb[c0 + co] - 2 * ad[0];
        int y1 = sb[c1 + co] - 2 * ad[1];
        int y2 = sb[c1 + co] - 2 * ad[2];
        int y3 = sb[c3 + co] - 2 * ad[3];
        float sc = scale[co], sh = shift[co];
        f4 o = { fmaf((float)y0, sc, sh), fmaf((float)y1, sc, sh),
                 fmaf((float)y2, sc, sh), fmaf((float)y3, sc, sh) };
        __builtin_nontemporal_store(o, (f4*)(on + (size_t)u * HWS));
    }
}

// ---------- pass B (slow/generic) ----------
__global__ void __launch_bounds__(256, 2) convnorm_slow(
        const unsigned* __restrict__ xs, const unsigned* __restrict__ xnz,
        const unsigned* __restrict__ wsg, const unsigned* __restrict__ wnz,
        const int* __restrict__ flagw, const int* __restrict__ flagz,
        const float* __restrict__ scale, const float* __restrict__ shift,
        float* __restrict__ out) {
    if ((*flagw) && !(*flagz)) return;
    int cobase = (blockIdx.x & 3) * 8;
    int sid = (blockIdx.x >> 2) * 256 + threadIdx.x;
    int n = sid / SPI, rem = sid - n * SPI;
    int h = rem / SPR, w0 = (rem - h * SPR) * 4;
    size_t off = (size_t)n * IMGW + h * PITCH + w0;

    unsigned a0[6], a1[6], a2[6], z0[6], z1[6], z2[6];
    loadwin(xs + off, a0); loadwin(xs + off + PITCH, a1); loadwin(xs + off + 2*PITCH, a2);
    loadwin(xnz + off, z0); loadwin(xnz + off + PITCH, z1); loadwin(xnz + off + 2*PITCH, z2);

    float* on = out + (size_t)(n * CC + cobase) * HWS + h * WWID + w0;
    #pragma unroll
    for (int u = 0; u < 8; ++u) {
        int co = cobase + u;
        int y[4];
        y4_slowc(a0, a1, a2, z0, z1, z2, wsg + co * 9, wnz + co * 9, y);
        float sc = scale[co], sh = shift[co];
        f4 o = { fmaf((float)y[0], sc, sh), fmaf((float)y[1], sc, sh),
                 fmaf((float)y[2], sc, sh), fmaf((float)y[3], sc, sh) };
        __builtin_nontemporal_store(o, (f4*)(on + (size_t)u * HWS));
    }
}

extern "C" void kernel_launch(void* const* d_in, const int* in_sizes, int n_in,
                              void* d_out, int out_size, void* d_ws, size_t ws_size,
                              hipStream_t stream) {
    const float* x     = (const float*)d_in[0];
    const float* w     = (const float*)d_in[1];
    const float* gamma = (const float*)d_in[2];
    const float* beta  = (const float*)d_in[3];
    float* out = (float*)d_out;

    char* ws = (char*)d_ws;
    unsigned* wsg            = (unsigned*)(ws + WS_WSIGN);
    unsigned* wnz            = (unsigned*)(ws + WS_WNZ);
    int* baset               = (int*)(ws + WS_BASE);
    int* flagw               = (int*)(ws + WS_FLAGW);
    int* flagz               = (int*)(ws + WS_FLAGZ);
    int* s_sum               = (int*)(ws + WS_SSUM);
    unsigned long long* s_sq = (unsigned long long*)(ws + WS_SSQ);
    float* scale             = (float*)(ws + WS_SCALE);
    float* shift             = (float*)(ws + WS_SHIFT);
    unsigned* xsb            = (unsigned*)(ws + WS_XS);
    unsigned* xzb            = (unsigned*)(ws + WS_XNZ);

    // zero flagz + stat accumulators, and the padded bit images (halo must be 0)
    hipMemsetAsync(ws + WS_FLAGZ, 0, WS_SCALE - WS_FLAGZ, stream);
    hipMemsetAsync(ws + WS_XS, 0, (size_t)NB * IMGW * 4 * 2, stream);

    pack_w  <<<1, 320, 0, stream>>>(w, wsg, wnz, flagw, baset);
    pack_x4 <<<STRIPS / 256, 256, 0, stream>>>(x, xsb, xzb, flagz);

    int cgrid = STRIPS / 256 * 4;
    convstats_fast<<<cgrid, 256, 0, stream>>>(xsb, wsg, baset, flagw, flagz, s_sum, s_sq);
    convstats_slow<<<cgrid, 256, 0, stream>>>(xsb, xzb, wsg, wnz, flagw, flagz, s_sum, s_sq);
    bfinal  <<<1, 64, 0, stream>>>(s_sum, s_sq, gamma, beta, scale, shift);
    convnorm_fast<<<cgrid, 256, 0, stream>>>(xsb, wsg, baset, flagw, flagz, scale, shift, out);
    convnorm_slow<<<cgrid, 256, 0, stream>>>(xsb, xzb, wsg, wnz, flagw, flagz, scale, shift, out);
}

// Round 5
// 84.500 us; speedup vs baseline: 1.7568x; 1.0855x over previous
//
#include <hip/hip_runtime.h>
#include <stdint.h>

#define NB 16
#define CC 32
#define HH 224
#define WWID 224
#define HWS (HH*WWID)          // 50176
#define NHWT (NB*HWS)          // 802816
#define STRIPS (NHWT/4)        // 200704 (1x4 pixel strips)
#define SPI (HWS/4)            // 12544 strips per image
#define SPR (WWID/4)           // 56 strips per row

// padded packed-bit image: 1-col left halo (col idx = 1+w), rows = 1+h, zero border
#define PITCH 232              // dwords per padded row (16B-aligned rows)
#define PROWS 226
#define IMGW (PITCH*PROWS)     // 52432 dwords per padded image

typedef float    f4 __attribute__((ext_vector_type(4)));
typedef unsigned u4 __attribute__((ext_vector_type(4)));
typedef unsigned u2 __attribute__((ext_vector_type(2)));

// workspace layout (bytes)
#define WS_WSIGN 0                       // 288 * 4
#define WS_WNZ   2048                    // 288 * 4
#define WS_BASE  4096                    // 288 * 4 (9 classes x 32 co)
#define WS_FLAGW 5248
#define WS_FLAGZ 5252
#define WS_SSUM  5376                    // 32 * int
#define WS_SSQ   5632                    // 32 * ull (8-aligned)
#define WS_SCALE 5888                    // 32 * float
#define WS_SHIFT 6016                    // 32 * float
#define WS_XS    8192                    // NB * IMGW * 4 = 3,355,648
#define WS_XNZ   (8192 + (size_t)NB*IMGW*4)

// ---------- pack weights + flags + base table + zero accumulators ----------
__global__ void pack_w(const float* __restrict__ w, unsigned* __restrict__ wsg,
                       unsigned* __restrict__ wnz, int* __restrict__ flagw,
                       int* __restrict__ baset, int* __restrict__ s_sum,
                       unsigned long long* __restrict__ s_sq, int* __restrict__ flagz) {
    __shared__ unsigned s_sg[288];
    __shared__ int allnz;
    if (threadIdx.x == 0) { allnz = 1; *flagz = 0; }
    if (threadIdx.x < CC) { s_sum[threadIdx.x] = 0; s_sq[threadIdx.x] = 0ull; }
    __syncthreads();
    int k = threadIdx.x;
    if (k < 288) {
        int co = k / 9, tap = k % 9;
        unsigned bits = 0, nz = 0;
        for (int ci = 0; ci < CC; ++ci) {
            float v = w[(co * CC + ci) * 9 + tap];
            bits |= (v > 0.f ? 1u : 0u) << ci;
            nz   |= (v != 0.f ? 1u : 0u) << ci;
        }
        wsg[k] = bits; wnz[k] = nz; s_sg[k] = bits;
        if (nz != 0xffffffffu) atomicAnd(&allnz, 0);
    }
    __syncthreads();
    if (threadIdx.x == 0) *flagw = allnz;
    if (k < 288) {
        int cls = k >> 5, co = k & 31;
        int hc = cls / 3, wc = cls % 3;
        int nv = 0, corr = 0;
        #pragma unroll
        for (int kh = 0; kh < 3; ++kh)
            #pragma unroll
            for (int kw = 0; kw < 3; ++kw) {
                bool inv = (hc == 0 && kh == 0) || (hc == 2 && kh == 2) ||
                           (wc == 0 && kw == 0) || (wc == 2 && kw == 2);
                if (inv) corr += __popc(s_sg[co * 9 + kh * 3 + kw]);
                else     nv++;
            }
        baset[k] = 32 * nv + 2 * corr;   // y = base - 2*sum9 popc(xor), halo xb = 0
    }
}

// ---------- pack x into padded sign/nz bit images (+ halo zeroing) ----------
__global__ void __launch_bounds__(256) pack_x4(const float* __restrict__ x,
                                               unsigned* __restrict__ xs,
                                               unsigned* __restrict__ xnz,
                                               int* __restrict__ flagz) {
    int t = blockIdx.x * 256 + threadIdx.x;     // strip id
    int n = t / SPI, rem = t - n * SPI;
    int h = rem / SPR, w0 = (rem - h * SPR) * 4;
    const float* base = x + (size_t)n * CC * HWS + h * WWID + w0;
    unsigned b0=0,b1=0,b2=0,b3=0, z0=0,z1=0,z2=0,z3=0;
    #pragma unroll
    for (int c = 0; c < CC; ++c) {
        f4 v = __builtin_nontemporal_load((const f4*)(base + (size_t)c * HWS));
        b0 |= (v.x > 0.f ? (1u<<c) : 0u);  z0 |= (v.x != 0.f ? (1u<<c) : 0u);
        b1 |= (v.y > 0.f ? (1u<<c) : 0u);  z1 |= (v.y != 0.f ? (1u<<c) : 0u);
        b2 |= (v.z > 0.f ? (1u<<c) : 0u);  z2 |= (v.z != 0.f ? (1u<<c) : 0u);
        b3 |= (v.w > 0.f ? (1u<<c) : 0u);  z3 |= (v.w != 0.f ? (1u<<c) : 0u);
    }
    size_t rowb = (size_t)n * IMGW + (h + 1) * PITCH;
    size_t d = rowb + 1 + w0;
    xs[d+0]=b0; xs[d+1]=b1; xs[d+2]=b2; xs[d+3]=b3;
    xnz[d+0]=z0; xnz[d+1]=z1; xnz[d+2]=z2; xnz[d+3]=z3;

    // halo zeroing (each halo cell written exactly once across the grid)
    if (w0 == 0)        { xs[rowb] = 0;       xnz[rowb] = 0; }        // left col, this row
    if (w0 == WWID - 4) { xs[rowb + 225] = 0; xnz[rowb + 225] = 0; }  // right col, this row
    if (h == 0) {                                                     // top halo row (row 0)
        size_t tr = (size_t)n * IMGW;
        #pragma unroll
        for (int j = 0; j < 4; ++j) { xs[tr + 1 + w0 + j] = 0; xnz[tr + 1 + w0 + j] = 0; }
        if (w0 == 0)        { xs[tr] = 0;       xnz[tr] = 0; }
        if (w0 == WWID - 4) { xs[tr + 225] = 0; xnz[tr + 225] = 0; }
    }
    if (h == HH - 1) {                                                // bottom halo row (row 225)
        size_t br = (size_t)n * IMGW + (size_t)(PROWS - 1) * PITCH;
        #pragma unroll
        for (int j = 0; j < 4; ++j) { xs[br + 1 + w0 + j] = 0; xnz[br + 1 + w0 + j] = 0; }
        if (w0 == 0)        { xs[br] = 0;       xnz[br] = 0; }
        if (w0 == WWID - 4) { xs[br + 225] = 0; xnz[br + 225] = 0; }
    }

    bool hasz = (z0 & z1 & z2 & z3) != 0xffffffffu;
    if (__any(hasz) && (threadIdx.x & 63) == 0) atomicOr(flagz, 1);
}

// ---------- window load: 6 dwords of one padded row (aligned x4 + x2) ----------
__device__ __forceinline__ void loadwin(const unsigned* __restrict__ p, unsigned a[6]) {
    u4 lo = *(const u4*)p;          // cols w0..w0+3 (16B aligned)
    u2 hi = *(const u2*)(p + 4);    // cols w0+4..w0+5 (8B aligned)
    a[0]=lo.x; a[1]=lo.y; a[2]=lo.z; a[3]=lo.w; a[4]=hi.x; a[5]=hi.y;
}

// ---------- 4-px xor-popcount sums for one cout ----------
__device__ __forceinline__ void ad4(const unsigned a0[6], const unsigned a1[6],
                                    const unsigned a2[6],
                                    const unsigned* __restrict__ q, int ad[4]) {
    unsigned q0=q[0],q1=q[1],q2=q[2],q3=q[3],q4=q[4],q5=q[5],q6=q[6],q7=q[7],q8=q[8];
    #pragma unroll
    for (int px = 0; px < 4; ++px) {
        ad[px] = __popc(a0[px]^q0) + __popc(a0[px+1]^q1) + __popc(a0[px+2]^q2)
               + __popc(a1[px]^q3) + __popc(a1[px+1]^q4) + __popc(a1[px+2]^q5)
               + __popc(a2[px]^q6) + __popc(a2[px+1]^q7) + __popc(a2[px+2]^q8);
    }
}

// ---------- generic (zeros-allowed) 4-px conv for one cout ----------
__device__ __forceinline__ void y4_slowc(const unsigned a0[6], const unsigned a1[6],
                                         const unsigned a2[6], const unsigned z0[6],
                                         const unsigned z1[6], const unsigned z2[6],
                                         const unsigned* __restrict__ qs,
                                         const unsigned* __restrict__ qz, int y[4]) {
    #pragma unroll
    for (int px = 0; px < 4; ++px) {
        int am = 0, ad = 0;
        #pragma unroll
        for (int kw = 0; kw < 3; ++kw) {
            unsigned m0 = z0[px+kw] & qz[kw];
            unsigned m1 = z1[px+kw] & qz[3+kw];
            unsigned m2 = z2[px+kw] & qz[6+kw];
            am += __popc(m0) + __popc(m1) + __popc(m2);
            ad += __popc((a0[px+kw]^qs[kw])   & m0)
                + __popc((a1[px+kw]^qs[3+kw]) & m1)
                + __popc((a2[px+kw]^qs[6+kw]) & m2);
        }
        y[px] = am - 2 * ad;
    }
}

// ---------- pass A: conv + exact per-channel stats, 8 couts/block ----------
__global__ void __launch_bounds__(256, 8) convstats(
        const unsigned* __restrict__ xs, const unsigned* __restrict__ xnz,
        const unsigned* __restrict__ wsg, const unsigned* __restrict__ wnz,
        const int* __restrict__ baset, const int* __restrict__ flagw,
        const int* __restrict__ flagz, int* __restrict__ s_sum,
        unsigned long long* __restrict__ s_sq) {
    __shared__ int sb[288];
    __shared__ int ls[4][8], lq[4][8];
    for (int i = threadIdx.x; i < 288; i += 256) sb[i] = baset[i];
    __syncthreads();

    int cobase = (blockIdx.x & 3) * 8;
    int sid = (blockIdx.x >> 2) * 256 + threadIdx.x;
    int n = sid / SPI, rem = sid - n * SPI;
    int h = rem / SPR, w0 = (rem - h * SPR) * 4;
    size_t off = (size_t)n * IMGW + h * PITCH + w0;

    unsigned a0[6], a1[6], a2[6];
    loadwin(xs + off, a0); loadwin(xs + off + PITCH, a1); loadwin(xs + off + 2*PITCH, a2);

    int sacc[8], qacc[8];
    bool fast = (*flagw != 0) && (*flagz == 0);
    if (fast) {
        int hc = (h == 0) ? 0 : ((h == HH-1) ? 6 : 3);
        int c0 = (hc + ((w0 == 0) ? 0 : 1)) * 32;
        int c1 = (hc + 1) * 32;
        int c3 = (hc + ((w0 == WWID-4) ? 2 : 1)) * 32;
        #pragma unroll
        for (int u = 0; u < 8; ++u) {
            int co = cobase + u;
            int ad[4];
            ad4(a0, a1, a2, wsg + co * 9, ad);
            int y0 = sb[c0 + co] - 2 * ad[0];
            int y1 = sb[c1 + co] - 2 * ad[1];
            int y2 = sb[c1 + co] - 2 * ad[2];
            int y3 = sb[c3 + co] - 2 * ad[3];
            sacc[u] = y0 + y1 + y2 + y3;
            qacc[u] = y0*y0 + y1*y1 + y2*y2 + y3*y3;
        }
    } else {
        unsigned z0[6], z1[6], z2[6];
        loadwin(xnz + off, z0); loadwin(xnz + off + PITCH, z1); loadwin(xnz + off + 2*PITCH, z2);
        #pragma unroll
        for (int u = 0; u < 8; ++u) {
            int co = cobase + u;
            int y[4];
            y4_slowc(a0, a1, a2, z0, z1, z2, wsg + co * 9, wnz + co * 9, y);
            sacc[u] = y[0]+y[1]+y[2]+y[3];
            qacc[u] = y[0]*y[0]+y[1]*y[1]+y[2]*y[2]+y[3]*y[3];
        }
    }

    #pragma unroll
    for (int off2 = 32; off2; off2 >>= 1) {
        #pragma unroll
        for (int u = 0; u < 8; ++u) {
            sacc[u] += __shfl_down(sacc[u], off2);
            qacc[u] += __shfl_down(qacc[u], off2);   // wave sum <= 64*4*288^2, fits int32
        }
    }
    int wid = threadIdx.x >> 6, lane = threadIdx.x & 63;
    if (lane == 0) {
        #pragma unroll
        for (int u = 0; u < 8; ++u) { ls[wid][u] = sacc[u]; lq[wid][u] = qacc[u]; }
    }
    __syncthreads();
    if (threadIdx.x < 8) {
        int u = threadIdx.x;
        int S = ls[0][u] + ls[1][u] + ls[2][u] + ls[3][u];
        long long Q = (long long)lq[0][u] + lq[1][u] + lq[2][u] + lq[3][u];
        atomicAdd(&s_sum[cobase + u], S);
        atomicAdd(&s_sq[cobase + u], (unsigned long long)Q);
    }
}

// ---------- finalize BN ----------
__global__ void bfinal(const int* __restrict__ s_sum,
                       const unsigned long long* __restrict__ s_sq,
                       const float* __restrict__ gamma, const float* __restrict__ beta,
                       float* __restrict__ scale, float* __restrict__ shift) {
    int c = threadIdx.x;
    if (c >= CC) return;
    double mean = (double)s_sum[c] / (double)NHWT;
    double var  = (double)(long long)s_sq[c] / (double)NHWT - mean * mean;
    float inv = (float)(1.0 / sqrt(var + 1e-5));
    float g = gamma[c] * inv;
    scale[c] = g;
    shift[c] = beta[c] - (float)mean * g;
}

// ---------- pass B: conv + normalize + nt store, 8 couts/block ----------
__global__ void __launch_bounds__(256, 8) convnorm(
        const unsigned* __restrict__ xs, const unsigned* __restrict__ xnz,
        const unsigned* __restrict__ wsg, const unsigned* __restrict__ wnz,
        const int* __restrict__ baset, const int* __restrict__ flagw,
        const int* __restrict__ flagz, const float* __restrict__ scale,
        const float* __restrict__ shift, float* __restrict__ out) {
    __shared__ int sb[288];
    for (int i = threadIdx.x; i < 288; i += 256) sb[i] = baset[i];
    __syncthreads();

    int cobase = (blockIdx.x & 3) * 8;
    int sid = (blockIdx.x >> 2) * 256 + threadIdx.x;
    int n = sid / SPI, rem = sid - n * SPI;
    int h = rem / SPR, w0 = (rem - h * SPR) * 4;
    size_t off = (size_t)n * IMGW + h * PITCH + w0;

    unsigned a0[6], a1[6], a2[6];
    loadwin(xs + off, a0); loadwin(xs + off + PITCH, a1); loadwin(xs + off + 2*PITCH, a2);

    float* on = out + (size_t)(n * CC + cobase) * HWS + h * WWID + w0;
    bool fast = (*flagw != 0) && (*flagz == 0);
    if (fast) {
        int hc = (h == 0) ? 0 : ((h == HH-1) ? 6 : 3);
        int c0 = (hc + ((w0 == 0) ? 0 : 1)) * 32;
        int c1 = (hc + 1) * 32;
        int c3 = (hc + ((w0 == WWID-4) ? 2 : 1)) * 32;
        #pragma unroll
        for (int u = 0; u < 8; ++u) {
            int co = cobase + u;
            int ad[4];
            ad4(a0, a1, a2, wsg + co * 9, ad);
            int y0 = sb[c0 + co] - 2 * ad[0];
            int y1 = sb[c1 + co] - 2 * ad[1];
            int y2 = sb[c1 + co] - 2 * ad[2];
            int y3 = sb[c3 + co] - 2 * ad[3];
            float sc = scale[co], sh = shift[co];
            f4 o = { fmaf((float)y0, sc, sh), fmaf((float)y1, sc, sh),
                     fmaf((float)y2, sc, sh), fmaf((float)y3, sc, sh) };
            __builtin_nontemporal_store(o, (f4*)(on + (size_t)u * HWS));
        }
    } else {
        unsigned z0[6], z1[6], z2[6];
        loadwin(xnz + off, z0); loadwin(xnz + off + PITCH, z1); loadwin(xnz + off + 2*PITCH, z2);
        #pragma unroll
        for (int u = 0; u < 8; ++u) {
            int co = cobase + u;
            int y[4];
            y4_slowc(a0, a1, a2, z0, z1, z2, wsg + co * 9, wnz + co * 9, y);
            float sc = scale[co], sh = shift[co];
            f4 o = { fmaf((float)y[0], sc, sh), fmaf((float)y[1], sc, sh),
                     fmaf((float)y[2], sc, sh), fmaf((float)y[3], sc, sh) };
            __builtin_nontemporal_store(o, (f4*)(on + (size_t)u * HWS));
        }
    }
}

extern "C" void kernel_launch(void* const* d_in, const int* in_sizes, int n_in,
                              void* d_out, int out_size, void* d_ws, size_t ws_size,
                              hipStream_t stream) {
    const float* x     = (const float*)d_in[0];
    const float* w     = (const float*)d_in[1];
    const float* gamma = (const float*)d_in[2];
    const float* beta  = (const float*)d_in[3];
    float* out = (float*)d_out;

    char* ws = (char*)d_ws;
    unsigned* wsg            = (unsigned*)(ws + WS_WSIGN);
    unsigned* wnz            = (unsigned*)(ws + WS_WNZ);
    int* baset               = (int*)(ws + WS_BASE);
    int* flagw               = (int*)(ws + WS_FLAGW);
    int* flagz               = (int*)(ws + WS_FLAGZ);
    int* s_sum               = (int*)(ws + WS_SSUM);
    unsigned long long* s_sq = (unsigned long long*)(ws + WS_SSQ);
    float* scale             = (float*)(ws + WS_SCALE);
    float* shift             = (float*)(ws + WS_SHIFT);
    unsigned* xsb            = (unsigned*)(ws + WS_XS);
    unsigned* xzb            = (unsigned*)(ws + WS_XNZ);

    int cgrid = STRIPS / 256 * 4;
    pack_w   <<<1, 320, 0, stream>>>(w, wsg, wnz, flagw, baset, s_sum, s_sq, flagz);
    pack_x4  <<<STRIPS / 256, 256, 0, stream>>>(x, xsb, xzb, flagz);
    convstats<<<cgrid, 256, 0, stream>>>(xsb, xzb, wsg, wnz, baset, flagw, flagz, s_sum, s_sq);
    bfinal   <<<1, 64, 0, stream>>>(s_sum, s_sq, gamma, beta, scale, shift);
    convnorm <<<cgrid, 256, 0, stream>>>(xsb, xzb, wsg, wnz, baset, flagw, flagz,
                                         scale, shift, out);
}